// Round 3
// baseline (347.911 us; speedup 1.0000x reference)
//
#include <hip/hip_runtime.h>

// Problem constants: V=100000, H=128, B=1024, L=512
#define V_TOK 100000
#define GAT_H 128
#define GAT_L 512
#define GAT_B 1024
#define CHUNK 8   // consecutive positions per wave; loads CHUNK+1 rows instead of 2*CHUNK

typedef float v2f __attribute__((ext_vector_type(2)));

__device__ __forceinline__ float readlane_f(float v, int l) {
    return __int_as_float(__builtin_amdgcn_readlane(__float_as_int(v), l));
}

// ---- kernel 0: S1 = sum(a1), S2 = sum(a2) -> sbuf[0..1] (one wave) ----
__global__ void k_sums(const float* __restrict__ a, float* __restrict__ sbuf) {
    const int lane = threadIdx.x & 63;
    const float2 a1 = ((const float2*)a)[lane];
    const float2 a2 = ((const float2*)(a + GAT_H))[lane];
    float s1 = a1.x + a1.y, s2 = a2.x + a2.y;
    #pragma unroll
    for (int m = 32; m >= 1; m >>= 1) {
        s1 += __shfl_xor(s1, m, 64);
        s2 += __shfl_xor(s2, m, 64);
    }
    if (lane == 0) { sbuf[0] = s1; sbuf[1] = s2; }
}

// ---- main kernel. One wave per CHUNK consecutive positions of one b. ----
// Fused: the former k_tok pass (separate 51.2 MB emb sweep building t1/t2
// token-dot tables) is folded in. Each emb row is already in registers here,
// so its a1/a2 dots are computed with a 6-round butterfly reduction (~26 cy
// per row) on the otherwise-idle VALU pipe. This removes a serial ~15 us
// dispatch AND the dependent t1[tok]/t2[tok] gather hop from the per-wave
// chain. k_main itself is memory-efficiency-bound (random 512 B gathers
// mixed with the 268 MB streaming write), so the extra VALU should absorb.
__global__ __launch_bounds__(256) void k_main(const float* __restrict__ emb,
                                              const float* __restrict__ a,
                                              const int* __restrict__ seq,
                                              const int* __restrict__ seq_l,
                                              const float* __restrict__ sbuf,
                                              float* __restrict__ out) {
    const int wid  = (blockIdx.x * blockDim.x + threadIdx.x) >> 6;
    const int lane = threadIdx.x & 63;
    const int b  = wid >> 6;                 // L/CHUNK = 64 chunks per sequence
    const int l0 = (wid & 63) * CHUNK;
    if (b >= GAT_B) return;

    const int sl = __builtin_amdgcn_readfirstlane(seq_l[b]);
    const float S1 = sbuf[0], S2 = sbuf[1];
    const float2 A1 = ((const float2*)a)[lane];          // a1[2*lane .. 2*lane+1]
    const float2 A2 = ((const float2*)(a + GAT_H))[lane];

    // Prefetch the chunk's 9 tokens in one vector load (lane i -> token l0+i;
    // lanes 9..63 duplicate lane 8). Last chunk clamps 512->511; that slot is
    // only consumed when need_next at k=7 requires valid(l=511), which is
    // impossible (sl <= 511), so the clamped value is never used.
    int li = l0 + (lane < 9 ? lane : 8);
    if (li > GAT_L - 1) li = GAT_L - 1;
    const int tokv = seq[b * GAT_L + li];

    const int tk0 = __builtin_amdgcn_readlane(tokv, 0);
    float2 R = ((const float2*)(emb + (size_t)tk0 * GAT_H))[lane];
    // In-place token dots for row 0: t1c = emb[tok0].a1, t2c = emb[tok0].a2
    float t1c = R.x * A1.x + R.y * A1.y;
    float t2c = R.x * A2.x + R.y * A2.y;
    #pragma unroll
    for (int m = 32; m >= 1; m >>= 1) {
        t1c += __shfl_xor(t1c, m, 64);
        t2c += __shfl_xor(t2c, m, 64);
    }
    float2* obase = (float2*)(out + ((size_t)b * GAT_L + l0) * GAT_H);

    #pragma unroll
    for (int k = 0; k < CHUNK; ++k) {
        const int l = l0 + k;
        const bool valid = (l < sl - 1);            // wave-uniform
        const bool need_next = valid || (k < CHUNK - 1);
        float2 Rn; float t1n = 0.f, t2n = 0.f;
        if (need_next) {
            const int tokn = __builtin_amdgcn_readlane(tokv, k + 1);  // SGPR
            Rn  = ((const float2*)(emb + (size_t)tokn * GAT_H))[lane];
            t1n = Rn.x * A1.x + Rn.y * A1.y;        // dots of the next row,
            t2n = Rn.x * A2.x + Rn.y * A2.y;        // butterfly-reduced in regs
            #pragma unroll
            for (int m = 32; m >= 1; m >>= 1) {
                t1n += __shfl_xor(t1n, m, 64);
                t2n += __shfl_xor(t2n, m, 64);
            }
        }
        v2f o2;
        if (valid) {
            const float pos  = (float)(sl - l);
            const float posn = pos - 1.0f;
            const float d1  = t1c + pos * S1;
            const float d2  = t2c + pos * S2;
            const float d2n = t2n + posn * S2;     // next position's self-a2 dot
            const float s0 = d1 + d2, s1 = d1 + d2n;
            const float mx = fmaxf(s0, s1);
            const float p0 = __expf(s0 - mx), p1 = __expf(s1 - mx);
            const float inv = 1.0f / (p0 + p1);
            const float att0 = p0 * inv, att1 = p1 * inv;
            o2.x = att0 * (R.x + pos) + att1 * (Rn.x + posn);
            o2.y = att0 * (R.y + pos) + att1 * (Rn.y + posn);
        } else {
            o2.x = R.x;                             // out = raw embedding
            o2.y = R.y;
        }
        __builtin_nontemporal_store(o2, (v2f*)(obase + (size_t)k * 64 + lane));
        if (need_next) { R = Rn; t1c = t1n; t2c = t2n; }
    }
}

extern "C" void kernel_launch(void* const* d_in, const int* in_sizes, int n_in,
                              void* d_out, int out_size, void* d_ws, size_t ws_size,
                              hipStream_t stream) {
    const float* emb   = (const float*)d_in[0];
    const float* a     = (const float*)d_in[1];
    const int*   seq   = (const int*)d_in[2];
    const int*   seq_l = (const int*)d_in[3];
    float* out = (float*)d_out;

    float* sbuf = (float*)d_ws;             // 2 floats

    k_sums<<<1, 64, 0, stream>>>(a, sbuf);

    {   // main: B * (L/CHUNK) waves
        const int waves = GAT_B * (GAT_L / CHUNK);
        const int blocks = (waves * 64 + 255) / 256;
        k_main<<<blocks, 256, 0, stream>>>(emb, a, seq, seq_l, sbuf, out);
    }
}

// Round 4
// 334.446 us; speedup vs baseline: 1.0403x; 1.0403x over previous
//
#include <hip/hip_runtime.h>

// Problem constants: V=100000, H=128, B=1024, L=512
#define V_TOK 100000
#define GAT_H 128
#define GAT_L 512
#define GAT_B 1024
#define CHUNK 16  // consecutive positions per wave; loads CHUNK+1 rows instead of 2*CHUNK

typedef float v2f __attribute__((ext_vector_type(2)));

__device__ __forceinline__ float readlane_f(float v, int l) {
    return __int_as_float(__builtin_amdgcn_readlane(__float_as_int(v), l));
}

// ---- kernel 1: per-token dots t1[v]=emb[v].a1, t2[v]=emb[v].a2 ----
// Two tokens per wave: lanes 0-31 handle token 2w (float4 each = 512 B row),
// lanes 32-63 token 2w+1. One 1 KB load instruction per wave, 5-round
// butterfly within each 32-lane half. Wave id V/2 computes the a1/a2 sums
// (the former k_sums kernel, merged to save a dispatch).
__global__ __launch_bounds__(256) void k_tok(const float* __restrict__ emb,
                                             const float* __restrict__ a,
                                             float* __restrict__ t1,
                                             float* __restrict__ t2,
                                             float* __restrict__ sbuf) {
    const int wid  = (blockIdx.x * blockDim.x + threadIdx.x) >> 6;
    const int lane = threadIdx.x & 63;
    if (wid > V_TOK / 2) return;

    if (wid == V_TOK / 2) {
        // sums wave: S1 = sum(a1), S2 = sum(a2)
        const float2 a1 = ((const float2*)a)[lane];
        const float2 a2 = ((const float2*)(a + GAT_H))[lane];
        float s1 = a1.x + a1.y, s2 = a2.x + a2.y;
        #pragma unroll
        for (int m = 32; m >= 1; m >>= 1) {
            s1 += __shfl_xor(s1, m, 64);
            s2 += __shfl_xor(s2, m, 64);
        }
        if (lane == 0) { sbuf[0] = s1; sbuf[1] = s2; }
        return;
    }

    const int half = lane >> 5;           // which of the two tokens
    const int sub  = lane & 31;           // position within the row
    const int tok  = 2 * wid + half;
    const float4 e  = ((const float4*)(emb + (size_t)tok * GAT_H))[sub];
    const float4 A1 = ((const float4*)a)[sub];
    const float4 A2 = ((const float4*)(a + GAT_H))[sub];
    float d1 = e.x * A1.x + e.y * A1.y + e.z * A1.z + e.w * A1.w;
    float d2 = e.x * A2.x + e.y * A2.y + e.z * A2.z + e.w * A2.w;
    #pragma unroll
    for (int m = 16; m >= 1; m >>= 1) {   // stays within each 32-lane half
        d1 += __shfl_xor(d1, m, 64);
        d2 += __shfl_xor(d2, m, 64);
    }
    if (sub == 0) { t1[tok] = d1; t2[tok] = d2; }
}

// ---- kernel 2: main. One wave per CHUNK consecutive positions of one b. ----
// Round-2 structure (best: 343.6 us): token dots come from the t1/t2 tables
// (NOT recomputed in-place — round-3 showed the butterfly lands on the
// dependent chain and costs more than the k_tok pass it saves). All per-chunk
// scalar state (CHUNK+1 tokens + their dots) is prefetched with 3 vector
// loads, distributed via v_readlane. Rows stream through a 2-register window
// (low VGPR -> 8 waves/SIMD). CHUNK=16 cuts read amplification to 1.0625x.
__global__ __launch_bounds__(256) void k_main(const float* __restrict__ emb,
                                              const int* __restrict__ seq,
                                              const int* __restrict__ seq_l,
                                              const float* __restrict__ t1,
                                              const float* __restrict__ t2,
                                              const float* __restrict__ sbuf,
                                              float* __restrict__ out) {
    const int wid  = (blockIdx.x * blockDim.x + threadIdx.x) >> 6;
    const int lane = threadIdx.x & 63;
    const int n_chunks = GAT_L / CHUNK;               // 32
    const int b  = wid / n_chunks;
    const int l0 = (wid - b * n_chunks) * CHUNK;
    if (b >= GAT_B) return;

    const int sl = __builtin_amdgcn_readfirstlane(seq_l[b]);
    const float S1 = sbuf[0], S2 = sbuf[1];

    // Prefetch the chunk's CHUNK+1 tokens and dot-table entries.
    // Lane i (i<=CHUNK) -> token l0+i; higher lanes duplicate lane CHUNK
    // (same address -> broadcast, no extra lines). Last chunk clamps
    // 512->511; that slot is only consumed when need_next at k=CHUNK-1
    // requires valid(l=511), impossible since sl <= 511.
    int li = l0 + (lane < CHUNK + 1 ? lane : CHUNK);
    if (li > GAT_L - 1) li = GAT_L - 1;
    const int   tokv = seq[b * GAT_L + li];
    const float t1v  = t1[tokv];
    const float t2v  = t2[tokv];

    const int tk0 = __builtin_amdgcn_readlane(tokv, 0);
    float2 R   = ((const float2*)(emb + (size_t)tk0 * GAT_H))[lane];
    float  t1c = readlane_f(t1v, 0);
    float  t2c = readlane_f(t2v, 0);
    float2* obase = (float2*)(out + ((size_t)b * GAT_L + l0) * GAT_H);

    #pragma unroll
    for (int k = 0; k < CHUNK; ++k) {
        const int l = l0 + k;
        const bool valid = (l < sl - 1);              // wave-uniform
        const bool need_next = valid || (k < CHUNK - 1);
        float2 Rn; float t1n = 0.f, t2n = 0.f;
        if (need_next) {
            const int tokn = __builtin_amdgcn_readlane(tokv, k + 1);  // SGPR
            Rn  = ((const float2*)(emb + (size_t)tokn * GAT_H))[lane];
            t1n = readlane_f(t1v, k + 1);
            t2n = readlane_f(t2v, k + 1);
        }
        v2f o2;
        if (valid) {
            const float pos  = (float)(sl - l);
            const float posn = pos - 1.0f;
            const float d1  = t1c + pos * S1;
            const float d2  = t2c + pos * S2;
            const float d2n = t2n + posn * S2;        // next position's self-a2 dot
            const float s0 = d1 + d2, s1 = d1 + d2n;
            const float mx = fmaxf(s0, s1);
            const float p0 = __expf(s0 - mx), p1 = __expf(s1 - mx);
            const float inv = 1.0f / (p0 + p1);
            const float att0 = p0 * inv, att1 = p1 * inv;
            o2.x = att0 * (R.x + pos) + att1 * (Rn.x + posn);
            o2.y = att0 * (R.y + pos) + att1 * (Rn.y + posn);
        } else {
            o2.x = R.x;                               // out = raw embedding
            o2.y = R.y;
        }
        __builtin_nontemporal_store(o2, (v2f*)(obase + (size_t)k * 64 + lane));
        if (need_next) { R = Rn; t1c = t1n; t2c = t2n; }
    }
}

extern "C" void kernel_launch(void* const* d_in, const int* in_sizes, int n_in,
                              void* d_out, int out_size, void* d_ws, size_t ws_size,
                              hipStream_t stream) {
    const float* emb   = (const float*)d_in[0];
    const float* a     = (const float*)d_in[1];
    const int*   seq   = (const int*)d_in[2];
    const int*   seq_l = (const int*)d_in[3];
    float* out = (float*)d_out;

    float* t1   = (float*)d_ws;             // V floats
    float* t2   = t1 + V_TOK;               // V floats
    float* sbuf = t2 + V_TOK;               // 2 floats

    {   // per-token dots (2 tokens/wave) + merged sums wave
        const int waves = V_TOK / 2 + 1;
        const int blocks = (waves * 64 + 255) / 256;
        k_tok<<<blocks, 256, 0, stream>>>(emb, a, t1, t2, sbuf);
    }

    {   // main: B * (L/CHUNK) waves
        const int waves = GAT_B * (GAT_L / CHUNK);
        const int blocks = (waves * 64 + 255) / 256;
        k_main<<<blocks, 256, 0, stream>>>(emb, seq, seq_l, t1, t2, sbuf, out);
    }
}

// Round 5
// 331.941 us; speedup vs baseline: 1.0481x; 1.0075x over previous
//
#include <hip/hip_runtime.h>
#include <hip/hip_fp16.h>

// Problem constants: V=100000, H=128, B=1024, L=512
#define V_TOK 100000
#define GAT_H 128
#define GAT_L 512
#define GAT_B 1024
#define CHUNK 16  // consecutive positions per wave; loads CHUNK+1 rows instead of 2*CHUNK

typedef float v2f __attribute__((ext_vector_type(2)));

__device__ __forceinline__ float readlane_f(float v, int l) {
    return __int_as_float(__builtin_amdgcn_readlane(__float_as_int(v), l));
}

// ---- kernel 1: per-token dots td[v] = (emb[v].a1, emb[v].a2) ----
// Two tokens per wave (float4 loads, 1 KB/instr). When F16, also writes an
// fp16 shadow copy of emb (halves k_main's gather bytes: 512 B -> 256 B/row).
// Dots are computed from the f32 rows, so scores stay full precision.
// Wave id V/2 computes the a1/a2 sums (merged former k_sums dispatch).
template<int F16>
__global__ __launch_bounds__(256) void k_tok(const float* __restrict__ emb,
                                             const float* __restrict__ a,
                                             float2* __restrict__ td,
                                             __half* __restrict__ emb16,
                                             float* __restrict__ sbuf) {
    const int wid  = (blockIdx.x * blockDim.x + threadIdx.x) >> 6;
    const int lane = threadIdx.x & 63;
    if (wid > V_TOK / 2) return;

    if (wid == V_TOK / 2) {
        // sums wave: S1 = sum(a1), S2 = sum(a2)
        const float2 a1 = ((const float2*)a)[lane];
        const float2 a2 = ((const float2*)(a + GAT_H))[lane];
        float s1 = a1.x + a1.y, s2 = a2.x + a2.y;
        #pragma unroll
        for (int m = 32; m >= 1; m >>= 1) {
            s1 += __shfl_xor(s1, m, 64);
            s2 += __shfl_xor(s2, m, 64);
        }
        if (lane == 0) { sbuf[0] = s1; sbuf[1] = s2; }
        return;
    }

    const int half = lane >> 5;           // which of the two tokens
    const int sub  = lane & 31;           // position within the row (4 elems)
    const int tok  = 2 * wid + half;
    const float4 e  = ((const float4*)(emb + (size_t)tok * GAT_H))[sub];
    const float4 A1 = ((const float4*)a)[sub];
    const float4 A2 = ((const float4*)(a + GAT_H))[sub];

    if constexpr (F16) {
        __half2 h01 = __floats2half2_rn(e.x, e.y);
        __half2 h23 = __floats2half2_rn(e.z, e.w);
        uint2 u;
        u.x = *(const unsigned int*)&h01;
        u.y = *(const unsigned int*)&h23;
        ((uint2*)(emb16 + (size_t)tok * GAT_H))[sub] = u;   // 8 B/lane, 256 B/row
    }

    float d1 = e.x * A1.x + e.y * A1.y + e.z * A1.z + e.w * A1.w;
    float d2 = e.x * A2.x + e.y * A2.y + e.z * A2.z + e.w * A2.w;
    #pragma unroll
    for (int m = 16; m >= 1; m >>= 1) {   // stays within each 32-lane half
        d1 += __shfl_xor(d1, m, 64);
        d2 += __shfl_xor(d2, m, 64);
    }
    if (sub == 0) td[tok] = make_float2(d1, d2);
}

// ---- kernel 2: main. One wave per CHUNK consecutive positions of one b. ----
// Round-2/4 structure (best so far): token dots come from the packed td table
// (in-loop butterfly regressed in round 3 — it lands on the dependent chain).
// All per-chunk scalar state (CHUNK+1 tokens + their dots) prefetched with 2
// vector loads, distributed via v_readlane. Rows stream through a 2-register
// window (low VGPR -> high occupancy). F16: rows gathered from the fp16
// shadow (256 B/row), converted in-register; output math stays f32.
template<int F16>
__global__ __launch_bounds__(256) void k_main(const float* __restrict__ emb,
                                              const __half* __restrict__ emb16,
                                              const int* __restrict__ seq,
                                              const int* __restrict__ seq_l,
                                              const float2* __restrict__ td,
                                              const float* __restrict__ sbuf,
                                              float* __restrict__ out) {
    const int wid  = (blockIdx.x * blockDim.x + threadIdx.x) >> 6;
    const int lane = threadIdx.x & 63;
    const int n_chunks = GAT_L / CHUNK;               // 32
    const int b  = wid / n_chunks;
    const int l0 = (wid - b * n_chunks) * CHUNK;
    if (b >= GAT_B) return;

    const int sl = __builtin_amdgcn_readfirstlane(seq_l[b]);
    const float S1 = sbuf[0], S2 = sbuf[1];

    // Prefetch the chunk's CHUNK+1 tokens and packed dot-table entries.
    // Lane i (i<=CHUNK) -> token l0+i; higher lanes duplicate lane CHUNK.
    // Last chunk clamps 512->511; that slot is only consumed when need_next
    // at k=CHUNK-1 requires valid(l=511), impossible since sl <= 511.
    int li = l0 + (lane < CHUNK + 1 ? lane : CHUNK);
    if (li > GAT_L - 1) li = GAT_L - 1;
    const int    tokv = seq[b * GAT_L + li];
    const float2 tdv  = td[tokv];                     // one 8 B gather

    auto load_row = [&](int tok) -> float2 {
        if constexpr (F16) {
            const __half2 h = ((const __half2*)(emb16 + (size_t)tok * GAT_H))[lane];
            return __half22float2(h);
        } else {
            return ((const float2*)(emb + (size_t)tok * GAT_H))[lane];
        }
    };

    const int tk0 = __builtin_amdgcn_readlane(tokv, 0);
    float2 R   = load_row(tk0);
    float  t1c = readlane_f(tdv.x, 0);
    float  t2c = readlane_f(tdv.y, 0);
    float2* obase = (float2*)(out + ((size_t)b * GAT_L + l0) * GAT_H);

    #pragma unroll
    for (int k = 0; k < CHUNK; ++k) {
        const int l = l0 + k;
        const bool valid = (l < sl - 1);              // wave-uniform
        const bool need_next = valid || (k < CHUNK - 1);
        float2 Rn; float t1n = 0.f, t2n = 0.f;
        if (need_next) {
            const int tokn = __builtin_amdgcn_readlane(tokv, k + 1);  // SGPR
            Rn  = load_row(tokn);
            t1n = readlane_f(tdv.x, k + 1);
            t2n = readlane_f(tdv.y, k + 1);
        }
        v2f o2;
        if (valid) {
            const float pos  = (float)(sl - l);
            const float posn = pos - 1.0f;
            const float d1  = t1c + pos * S1;
            const float d2  = t2c + pos * S2;
            const float d2n = t2n + posn * S2;        // next position's self-a2 dot
            const float s0 = d1 + d2, s1 = d1 + d2n;
            const float mx = fmaxf(s0, s1);
            const float p0 = __expf(s0 - mx), p1 = __expf(s1 - mx);
            const float inv = 1.0f / (p0 + p1);
            const float att0 = p0 * inv, att1 = p1 * inv;
            o2.x = att0 * (R.x + pos) + att1 * (Rn.x + posn);
            o2.y = att0 * (R.y + pos) + att1 * (Rn.y + posn);
        } else {
            o2.x = R.x;                               // out = raw embedding
            o2.y = R.y;
        }
        __builtin_nontemporal_store(o2, (v2f*)(obase + (size_t)k * 64 + lane));
        if (need_next) { R = Rn; t1c = t1n; t2c = t2n; }
    }
}

extern "C" void kernel_launch(void* const* d_in, const int* in_sizes, int n_in,
                              void* d_out, int out_size, void* d_ws, size_t ws_size,
                              hipStream_t stream) {
    const float* emb   = (const float*)d_in[0];
    const float* a     = (const float*)d_in[1];
    const int*   seq   = (const int*)d_in[2];
    const int*   seq_l = (const int*)d_in[3];
    float* out = (float*)d_out;

    const size_t emb16_bytes = (size_t)V_TOK * GAT_H * sizeof(__half);  // 25.6 MB
    const size_t td_bytes    = (size_t)V_TOK * sizeof(float2);          // 800 KB
    const size_t need16      = emb16_bytes + td_bytes + 16;

    const int tok_waves  = V_TOK / 2 + 1;
    const int tok_blocks = (tok_waves * 64 + 255) / 256;
    const int main_waves  = GAT_B * (GAT_L / CHUNK);
    const int main_blocks = (main_waves * 64 + 255) / 256;

    if (ws_size >= need16) {
        __half* emb16 = (__half*)d_ws;
        float2* td    = (float2*)((char*)d_ws + emb16_bytes);
        float*  sbuf  = (float*)((char*)td + td_bytes);
        k_tok<1><<<tok_blocks, 256, 0, stream>>>(emb, a, td, emb16, sbuf);
        k_main<1><<<main_blocks, 256, 0, stream>>>(emb, emb16, seq, seq_l, td, sbuf, out);
    } else {
        // fp32 fallback (round-4 behavior) if workspace can't hold the shadow
        float2* td   = (float2*)d_ws;
        float*  sbuf = (float*)((char*)td + td_bytes);
        k_tok<0><<<tok_blocks, 256, 0, stream>>>(emb, a, td, nullptr, sbuf);
        k_main<0><<<main_blocks, 256, 0, stream>>>(emb, nullptr, seq, seq_l, td, sbuf, out);
    }
}

// Round 6
// 318.322 us; speedup vs baseline: 1.0930x; 1.0428x over previous
//
#include <hip/hip_runtime.h>
#include <hip/hip_fp16.h>

// Problem constants: V=100000, H=128, B=1024, L=512
#define V_TOK 100000
#define GAT_H 128
#define GAT_L 512
#define GAT_B 1024
#define CHUNK 16  // consecutive positions per wave; loads CHUNK+1 rows instead of 2*CHUNK

typedef float v2f __attribute__((ext_vector_type(2)));

__device__ __forceinline__ float readlane_f(float v, int l) {
    return __int_as_float(__builtin_amdgcn_readlane(__float_as_int(v), l));
}

// ---- kernel 1: per-token dots td[v] = (emb[v].a1, emb[v].a2) ----
// Two tokens per wave (float4 loads, 1 KB/instr). When F16, also writes an
// fp16 shadow copy of emb (k_main gathers 256 B rows, 1 VGPR per row).
// Dots are computed from the f32 rows, so scores stay full precision.
// Wave id V/2 computes the a1/a2 sums (merged former k_sums dispatch).
template<int F16>
__global__ __launch_bounds__(256) void k_tok(const float* __restrict__ emb,
                                             const float* __restrict__ a,
                                             float2* __restrict__ td,
                                             __half* __restrict__ emb16,
                                             float* __restrict__ sbuf) {
    const int wid  = (blockIdx.x * blockDim.x + threadIdx.x) >> 6;
    const int lane = threadIdx.x & 63;
    if (wid > V_TOK / 2) return;

    if (wid == V_TOK / 2) {
        // sums wave: S1 = sum(a1), S2 = sum(a2)
        const float2 a1 = ((const float2*)a)[lane];
        const float2 a2 = ((const float2*)(a + GAT_H))[lane];
        float s1 = a1.x + a1.y, s2 = a2.x + a2.y;
        #pragma unroll
        for (int m = 32; m >= 1; m >>= 1) {
            s1 += __shfl_xor(s1, m, 64);
            s2 += __shfl_xor(s2, m, 64);
        }
        if (lane == 0) { sbuf[0] = s1; sbuf[1] = s2; }
        return;
    }

    const int half = lane >> 5;           // which of the two tokens
    const int sub  = lane & 31;           // position within the row (4 elems)
    const int tok  = 2 * wid + half;
    const float4 e  = ((const float4*)(emb + (size_t)tok * GAT_H))[sub];
    const float4 A1 = ((const float4*)a)[sub];
    const float4 A2 = ((const float4*)(a + GAT_H))[sub];

    if constexpr (F16) {
        __half2 h01 = __floats2half2_rn(e.x, e.y);
        __half2 h23 = __floats2half2_rn(e.z, e.w);
        uint2 u;
        u.x = *(const unsigned int*)&h01;
        u.y = *(const unsigned int*)&h23;
        ((uint2*)(emb16 + (size_t)tok * GAT_H))[sub] = u;   // 8 B/lane, 256 B/row
    }

    float d1 = e.x * A1.x + e.y * A1.y + e.z * A1.z + e.w * A1.w;
    float d2 = e.x * A2.x + e.y * A2.y + e.z * A2.z + e.w * A2.w;
    #pragma unroll
    for (int m = 16; m >= 1; m >>= 1) {   // stays within each 32-lane half
        d1 += __shfl_xor(d1, m, 64);
        d2 += __shfl_xor(d2, m, 64);
    }
    if (sub == 0) td[tok] = make_float2(d1, d2);
}

// ---- kernel 2: main. One wave per CHUNK consecutive positions of one b. ----
// BURST structure: all CHUNK+1 row loads are issued unconditionally and
// back-to-back BEFORE the compute/store loop. Rationale: vmcnt retires
// strictly in order, so in the previous load->compute->store-per-iteration
// loop, waiting on the next row's load also forced the PREVIOUS nt-store's
// HBM ack onto the critical path (16 store-ack latencies per wave). With all
// loads issued first, no load wait can be blocked behind a store ack, and
// the compiler's fine-grained vmcnt(N) walks the in-order load queue freely.
// fp16 rows are 1 VGPR each -> 17 regs for the whole chunk, occupancy intact.
template<int F16>
__global__ __launch_bounds__(256) void k_main(const float* __restrict__ emb,
                                              const __half* __restrict__ emb16,
                                              const int* __restrict__ seq,
                                              const int* __restrict__ seq_l,
                                              const float2* __restrict__ td,
                                              const float* __restrict__ sbuf,
                                              float* __restrict__ out) {
    const int wid  = (blockIdx.x * blockDim.x + threadIdx.x) >> 6;
    const int lane = threadIdx.x & 63;
    const int n_chunks = GAT_L / CHUNK;               // 32
    const int b  = wid / n_chunks;
    const int l0 = (wid - b * n_chunks) * CHUNK;
    if (b >= GAT_B) return;

    const int sl = __builtin_amdgcn_readfirstlane(seq_l[b]);
    const float S1 = sbuf[0], S2 = sbuf[1];

    // Prefetch the chunk's CHUNK+1 tokens and packed dot-table entries.
    // Lane i (i<=CHUNK) -> token l0+i; higher lanes duplicate lane CHUNK.
    // Last chunk clamps 512->511; that row feeds only k=CHUNK-1's "next",
    // consumed only if valid(l=511) -- impossible since sl <= 511.
    int li = l0 + (lane < CHUNK + 1 ? lane : CHUNK);
    if (li > GAT_L - 1) li = GAT_L - 1;
    const int    tokv = seq[b * GAT_L + li];
    const float2 tdv  = td[tokv];                     // one 8 B gather

    // ---- burst: issue ALL row loads, no stores in between ----
    if constexpr (F16) {
        unsigned int rows[CHUNK + 1];                 // __half2 per lane
        #pragma unroll
        for (int k = 0; k <= CHUNK; ++k) {
            const int tk = __builtin_amdgcn_readlane(tokv, k);   // SGPR addr
            rows[k] = *((const unsigned int*)(emb16 + (size_t)tk * GAT_H) + lane);
        }
        float2* obase = (float2*)(out + ((size_t)b * GAT_L + l0) * GAT_H);
        #pragma unroll
        for (int k = 0; k < CHUNK; ++k) {
            const int l = l0 + k;
            const bool valid = (l < sl - 1);          // wave-uniform
            const float2 R  = __half22float2(*(const __half2*)&rows[k]);
            const float2 Rn = __half22float2(*(const __half2*)&rows[k + 1]);
            v2f o2;
            if (valid) {
                const float pos  = (float)(sl - l);
                const float posn = pos - 1.0f;
                const float d1  = readlane_f(tdv.x, k) + pos * S1;
                const float d2  = readlane_f(tdv.y, k) + pos * S2;
                const float d2n = readlane_f(tdv.y, k + 1) + posn * S2;
                const float s0 = d1 + d2, s1 = d1 + d2n;
                const float mx = fmaxf(s0, s1);
                const float p0 = __expf(s0 - mx), p1 = __expf(s1 - mx);
                const float inv = 1.0f / (p0 + p1);
                const float att0 = p0 * inv, att1 = p1 * inv;
                o2.x = att0 * (R.x + pos) + att1 * (Rn.x + posn);
                o2.y = att0 * (R.y + pos) + att1 * (Rn.y + posn);
            } else {
                o2.x = R.x;                           // out = raw embedding
                o2.y = R.y;
            }
            __builtin_nontemporal_store(o2, (v2f*)(obase + (size_t)k * 64 + lane));
        }
    } else {
        float2 rows[CHUNK + 1];
        #pragma unroll
        for (int k = 0; k <= CHUNK; ++k) {
            const int tk = __builtin_amdgcn_readlane(tokv, k);
            rows[k] = ((const float2*)(emb + (size_t)tk * GAT_H))[lane];
        }
        float2* obase = (float2*)(out + ((size_t)b * GAT_L + l0) * GAT_H);
        #pragma unroll
        for (int k = 0; k < CHUNK; ++k) {
            const int l = l0 + k;
            const bool valid = (l < sl - 1);
            const float2 R  = rows[k];
            const float2 Rn = rows[k + 1];
            v2f o2;
            if (valid) {
                const float pos  = (float)(sl - l);
                const float posn = pos - 1.0f;
                const float d1  = readlane_f(tdv.x, k) + pos * S1;
                const float d2  = readlane_f(tdv.y, k) + pos * S2;
                const float d2n = readlane_f(tdv.y, k + 1) + posn * S2;
                const float s0 = d1 + d2, s1 = d1 + d2n;
                const float mx = fmaxf(s0, s1);
                const float p0 = __expf(s0 - mx), p1 = __expf(s1 - mx);
                const float inv = 1.0f / (p0 + p1);
                const float att0 = p0 * inv, att1 = p1 * inv;
                o2.x = att0 * (R.x + pos) + att1 * (Rn.x + posn);
                o2.y = att0 * (R.y + pos) + att1 * (Rn.y + posn);
            } else {
                o2.x = R.x;
                o2.y = R.y;
            }
            __builtin_nontemporal_store(o2, (v2f*)(obase + (size_t)k * 64 + lane));
        }
    }
}

extern "C" void kernel_launch(void* const* d_in, const int* in_sizes, int n_in,
                              void* d_out, int out_size, void* d_ws, size_t ws_size,
                              hipStream_t stream) {
    const float* emb   = (const float*)d_in[0];
    const float* a     = (const float*)d_in[1];
    const int*   seq   = (const int*)d_in[2];
    const int*   seq_l = (const int*)d_in[3];
    float* out = (float*)d_out;

    const size_t emb16_bytes = (size_t)V_TOK * GAT_H * sizeof(__half);  // 25.6 MB
    const size_t td_bytes    = (size_t)V_TOK * sizeof(float2);          // 800 KB
    const size_t need16      = emb16_bytes + td_bytes + 16;

    const int tok_waves  = V_TOK / 2 + 1;
    const int tok_blocks = (tok_waves * 64 + 255) / 256;
    const int main_waves  = GAT_B * (GAT_L / CHUNK);
    const int main_blocks = (main_waves * 64 + 255) / 256;

    if (ws_size >= need16) {
        __half* emb16 = (__half*)d_ws;
        float2* td    = (float2*)((char*)d_ws + emb16_bytes);
        float*  sbuf  = (float*)((char*)td + td_bytes);
        k_tok<1><<<tok_blocks, 256, 0, stream>>>(emb, a, td, emb16, sbuf);
        k_main<1><<<main_blocks, 256, 0, stream>>>(emb, emb16, seq, seq_l, td, sbuf, out);
    } else {
        // fp32 fallback if workspace can't hold the shadow
        float2* td   = (float2*)d_ws;
        float*  sbuf = (float*)((char*)td + td_bytes);
        k_tok<0><<<tok_blocks, 256, 0, stream>>>(emb, a, td, nullptr, sbuf);
        k_main<0><<<main_blocks, 256, 0, stream>>>(emb, nullptr, seq, seq_l, td, sbuf, out);
    }
}

// Round 7
// 311.094 us; speedup vs baseline: 1.1183x; 1.0232x over previous
//
#include <hip/hip_runtime.h>

// Problem constants: V=100000, H=128, B=1024, L=512
#define V_TOK 100000
#define GAT_H 128
#define GAT_L 512
#define GAT_B 1024
#define CHUNK 16  // consecutive positions per wave; loads CHUNK+1 rows instead of 2*CHUNK

typedef float v2f __attribute__((ext_vector_type(2)));

__device__ __forceinline__ float readlane_f(float v, int l) {
    return __int_as_float(__builtin_amdgcn_readlane(__float_as_int(v), l));
}

// ---- kernel 1: per-token dots td[v] = (emb[v].a1, emb[v].a2) ----
// Two tokens per wave (float4 loads, 1 KB/instr). When FP8, also writes an
// OCP e4m3 shadow copy of emb: 128 B/row -> 2 cache lines per gather in
// k_main (vs 8 for f32). Dots are computed from the f32 rows, so SCORES stay
// full precision; only the convex combination of embedding values is
// quantized (|err| <= ~0.35 << absmax tol 2.0).
// Wave id V/2 computes the a1/a2 sums (merged former k_sums dispatch).
template<int FP8>
__global__ __launch_bounds__(256) void k_tok(const float* __restrict__ emb,
                                             const float* __restrict__ a,
                                             float2* __restrict__ td,
                                             unsigned char* __restrict__ emb8,
                                             float* __restrict__ sbuf) {
    const int wid  = (blockIdx.x * blockDim.x + threadIdx.x) >> 6;
    const int lane = threadIdx.x & 63;
    if (wid > V_TOK / 2) return;

    if (wid == V_TOK / 2) {
        // sums wave: S1 = sum(a1), S2 = sum(a2)
        const float2 a1 = ((const float2*)a)[lane];
        const float2 a2 = ((const float2*)(a + GAT_H))[lane];
        float s1 = a1.x + a1.y, s2 = a2.x + a2.y;
        #pragma unroll
        for (int m = 32; m >= 1; m >>= 1) {
            s1 += __shfl_xor(s1, m, 64);
            s2 += __shfl_xor(s2, m, 64);
        }
        if (lane == 0) { sbuf[0] = s1; sbuf[1] = s2; }
        return;
    }

    const int half = lane >> 5;           // which of the two tokens
    const int sub  = lane & 31;           // position within the row (4 elems)
    const int tok  = 2 * wid + half;
    const float4 e  = ((const float4*)(emb + (size_t)tok * GAT_H))[sub];
    const float4 A1 = ((const float4*)a)[sub];
    const float4 A2 = ((const float4*)(a + GAT_H))[sub];

    if constexpr (FP8) {
        // pack 4 elems -> 4 fp8 (e4m3) in one dword; row = 128 B = 32 dwords
        int p = 0;
        p = __builtin_amdgcn_cvt_pk_fp8_f32(e.x, e.y, p, false);  // low word
        p = __builtin_amdgcn_cvt_pk_fp8_f32(e.z, e.w, p, true);   // high word
        ((int*)(emb8 + (size_t)tok * GAT_H))[sub] = p;            // 4 B/lane
    }

    float d1 = e.x * A1.x + e.y * A1.y + e.z * A1.z + e.w * A1.w;
    float d2 = e.x * A2.x + e.y * A2.y + e.z * A2.z + e.w * A2.w;
    #pragma unroll
    for (int m = 16; m >= 1; m >>= 1) {   // stays within each 32-lane half
        d1 += __shfl_xor(d1, m, 64);
        d2 += __shfl_xor(d2, m, 64);
    }
    if (sub == 0) td[tok] = make_float2(d1, d2);
}

// ---- kernel 2: main. One wave per CHUNK consecutive positions of one b. ----
// Round-5 BURST structure (best: 318.3 us): all CHUNK+1 row loads issued
// unconditionally and back-to-back BEFORE the compute/store loop, so no load
// wait is ever blocked behind an nt-store ack (vmcnt retires in order).
// FP8: each gathered row is 128 B (2 B/lane, ushort), 2 cache lines -- halves
// the random read-line count vs fp16, and the 12.8 MB shadow retains far
// better in per-XCD L2 (4 MiB). Rows expand to f32 via v_cvt_pk_f32_fp8
// (1 VALU op) inside the compute loop. Scores use the exact f32 tables.
template<int FP8>
__global__ __launch_bounds__(256) void k_main(const float* __restrict__ emb,
                                              const unsigned char* __restrict__ emb8,
                                              const int* __restrict__ seq,
                                              const int* __restrict__ seq_l,
                                              const float2* __restrict__ td,
                                              const float* __restrict__ sbuf,
                                              float* __restrict__ out) {
    const int wid  = (blockIdx.x * blockDim.x + threadIdx.x) >> 6;
    const int lane = threadIdx.x & 63;
    const int n_chunks = GAT_L / CHUNK;               // 32
    const int b  = wid / n_chunks;
    const int l0 = (wid - b * n_chunks) * CHUNK;
    if (b >= GAT_B) return;

    const int sl = __builtin_amdgcn_readfirstlane(seq_l[b]);
    const float S1 = sbuf[0], S2 = sbuf[1];

    // Prefetch the chunk's CHUNK+1 tokens and packed dot-table entries.
    // Lane i (i<=CHUNK) -> token l0+i; higher lanes duplicate lane CHUNK.
    // Last chunk clamps 512->511; that row feeds only k=CHUNK-1's "next",
    // consumed only if valid(l=511) -- impossible since sl <= 511.
    int li = l0 + (lane < CHUNK + 1 ? lane : CHUNK);
    if (li > GAT_L - 1) li = GAT_L - 1;
    const int    tokv = seq[b * GAT_L + li];
    const float2 tdv  = td[tokv];                     // one 8 B gather

    float2* obase = (float2*)(out + ((size_t)b * GAT_L + l0) * GAT_H);

    if constexpr (FP8) {
        unsigned short rows[CHUNK + 1];               // 2 fp8 elems per lane
        #pragma unroll
        for (int k = 0; k <= CHUNK; ++k) {
            const int tk = __builtin_amdgcn_readlane(tokv, k);   // SGPR base
            rows[k] = *((const unsigned short*)(emb8 + (size_t)tk * GAT_H) + lane);
        }
        #pragma unroll
        for (int k = 0; k < CHUNK; ++k) {
            const int l = l0 + k;
            const bool valid = (l < sl - 1);          // wave-uniform
            const v2f R  = __builtin_amdgcn_cvt_pk_f32_fp8((int)rows[k],     false);
            const v2f Rn = __builtin_amdgcn_cvt_pk_f32_fp8((int)rows[k + 1], false);
            v2f o2;
            if (valid) {
                const float pos  = (float)(sl - l);
                const float posn = pos - 1.0f;
                const float d1  = readlane_f(tdv.x, k) + pos * S1;
                const float d2  = readlane_f(tdv.y, k) + pos * S2;
                const float d2n = readlane_f(tdv.y, k + 1) + posn * S2;
                const float s0 = d1 + d2, s1 = d1 + d2n;
                const float mx = fmaxf(s0, s1);
                const float p0 = __expf(s0 - mx), p1 = __expf(s1 - mx);
                const float inv = 1.0f / (p0 + p1);
                const float att0 = p0 * inv, att1 = p1 * inv;
                o2.x = att0 * (R.x + pos) + att1 * (Rn.x + posn);
                o2.y = att0 * (R.y + pos) + att1 * (Rn.y + posn);
            } else {
                o2.x = R.x;                           // out = raw embedding
                o2.y = R.y;
            }
            __builtin_nontemporal_store(o2, (v2f*)(obase + (size_t)k * 64 + lane));
        }
    } else {
        // f32 fallback: round-5 burst on the original table
        float2 rows[CHUNK + 1];
        #pragma unroll
        for (int k = 0; k <= CHUNK; ++k) {
            const int tk = __builtin_amdgcn_readlane(tokv, k);
            rows[k] = ((const float2*)(emb + (size_t)tk * GAT_H))[lane];
        }
        #pragma unroll
        for (int k = 0; k < CHUNK; ++k) {
            const int l = l0 + k;
            const bool valid = (l < sl - 1);
            const float2 R  = rows[k];
            const float2 Rn = rows[k + 1];
            v2f o2;
            if (valid) {
                const float pos  = (float)(sl - l);
                const float posn = pos - 1.0f;
                const float d1  = readlane_f(tdv.x, k) + pos * S1;
                const float d2  = readlane_f(tdv.y, k) + pos * S2;
                const float d2n = readlane_f(tdv.y, k + 1) + posn * S2;
                const float s0 = d1 + d2, s1 = d1 + d2n;
                const float mx = fmaxf(s0, s1);
                const float p0 = __expf(s0 - mx), p1 = __expf(s1 - mx);
                const float inv = 1.0f / (p0 + p1);
                const float att0 = p0 * inv, att1 = p1 * inv;
                o2.x = att0 * (R.x + pos) + att1 * (Rn.x + posn);
                o2.y = att0 * (R.y + pos) + att1 * (Rn.y + posn);
            } else {
                o2.x = R.x;
                o2.y = R.y;
            }
            __builtin_nontemporal_store(o2, (v2f*)(obase + (size_t)k * 64 + lane));
        }
    }
}

extern "C" void kernel_launch(void* const* d_in, const int* in_sizes, int n_in,
                              void* d_out, int out_size, void* d_ws, size_t ws_size,
                              hipStream_t stream) {
    const float* emb   = (const float*)d_in[0];
    const float* a     = (const float*)d_in[1];
    const int*   seq   = (const int*)d_in[2];
    const int*   seq_l = (const int*)d_in[3];
    float* out = (float*)d_out;

    const size_t emb8_bytes = (size_t)V_TOK * GAT_H;                    // 12.8 MB
    const size_t td_bytes   = (size_t)V_TOK * sizeof(float2);           // 800 KB
    const size_t need8      = emb8_bytes + td_bytes + 16;

    const int tok_waves  = V_TOK / 2 + 1;
    const int tok_blocks = (tok_waves * 64 + 255) / 256;
    const int main_waves  = GAT_B * (GAT_L / CHUNK);
    const int main_blocks = (main_waves * 64 + 255) / 256;

    if (ws_size >= need8) {
        unsigned char* emb8 = (unsigned char*)d_ws;
        float2* td   = (float2*)((char*)d_ws + emb8_bytes);
        float*  sbuf = (float*)((char*)td + td_bytes);
        k_tok<1><<<tok_blocks, 256, 0, stream>>>(emb, a, td, emb8, sbuf);
        k_main<1><<<main_blocks, 256, 0, stream>>>(emb, emb8, seq, seq_l, td, sbuf, out);
    } else {
        // f32 fallback if workspace can't hold the shadow
        float2* td   = (float2*)d_ws;
        float*  sbuf = (float*)((char*)td + td_bytes);
        k_tok<0><<<tok_blocks, 256, 0, stream>>>(emb, a, td, nullptr, sbuf);
        k_main<0><<<main_blocks, 256, 0, stream>>>(emb, nullptr, seq, seq_l, td, sbuf, out);
    }
}

// Round 8
// 304.499 us; speedup vs baseline: 1.1426x; 1.0217x over previous
//
#include <hip/hip_runtime.h>

// Problem constants: V=100000, H=128, B=1024, L=512
#define V_TOK 100000
#define GAT_H 128
#define GAT_L 512
#define GAT_B 1024
#define CHUNK 16  // consecutive positions per wave; loads CHUNK+1 rows

typedef float v2f __attribute__((ext_vector_type(2)));

__device__ __forceinline__ float readlane_f(float v, int l) {
    return __int_as_float(__builtin_amdgcn_readlane(__float_as_int(v), l));
}

// ---- kernel 1: per-token a2-dots t2[v] = emb[v].a2 (+ fp8 shadow) ----
// ALGEBRA: softmax([s0,s1]) depends only on s0-s1 = t2[tok_l]-t2[tok_{l+1}]+S2
// -- the a1 half of the weight vector cancels. Only the t2 table is needed.
// Two tokens per wave (float4 loads). FP8: also writes an OCP e4m3 shadow of
// emb (128 B/row, 2 lines/gather). Dots from f32 rows -> scores full precision.
// Wave id V/2 computes S2 = sum(a2) (merged sums dispatch).
template<int FP8>
__global__ __launch_bounds__(256) void k_tok(const float* __restrict__ emb,
                                             const float* __restrict__ a,
                                             float* __restrict__ t2,
                                             unsigned char* __restrict__ emb8,
                                             float* __restrict__ sbuf) {
    const int wid  = (blockIdx.x * blockDim.x + threadIdx.x) >> 6;
    const int lane = threadIdx.x & 63;
    if (wid > V_TOK / 2) return;

    if (wid == V_TOK / 2) {
        const float2 a2 = ((const float2*)(a + GAT_H))[lane];
        float s2 = a2.x + a2.y;
        #pragma unroll
        for (int m = 32; m >= 1; m >>= 1) s2 += __shfl_xor(s2, m, 64);
        if (lane == 0) sbuf[0] = s2;
        return;
    }

    const int half = lane >> 5;           // which of the two tokens
    const int sub  = lane & 31;           // position within the row (4 elems)
    const int tok  = 2 * wid + half;
    const float4 e  = ((const float4*)(emb + (size_t)tok * GAT_H))[sub];
    const float4 A2 = ((const float4*)(a + GAT_H))[sub];

    if constexpr (FP8) {
        int p = 0;
        p = __builtin_amdgcn_cvt_pk_fp8_f32(e.x, e.y, p, false);  // low word
        p = __builtin_amdgcn_cvt_pk_fp8_f32(e.z, e.w, p, true);   // high word
        ((int*)(emb8 + (size_t)tok * GAT_H))[sub] = p;            // 4 B/lane
    }

    float d2 = e.x * A2.x + e.y * A2.y + e.z * A2.z + e.w * A2.w;
    #pragma unroll
    for (int m = 16; m >= 1; m >>= 1) d2 += __shfl_xor(d2, m, 64);
    if (sub == 0) t2[tok] = d2;
}

// ---- kernel 2: main. One wave per CHUNK consecutive positions of one b. ----
// Round-6 BURST structure + VALU collapse. Previous loop redid ~25
// wave-uniform softmax ops in all 64 lanes, 16x per wave (~1050 cy issue --
// the real bottleneck; fp16/fp8 gather shrink only bought ~10 us combined).
// Now: lane k (k<16) computes position k's {att0, att1, c} ONCE:
//   delta = t2[tok_k] - t2[tok_{k+1}] + S2        (a1 cancels in s0-s1)
//   att1 = 1/(1+exp(delta)); att0 = 1-att1; c = pos - att1
//   (o = att0*R + att1*Rn + c, since att0*pos+att1*(pos-1) = pos-att1)
// invalid positions: att0=1, att1=0, c=0 -> branchless store loop, o == R.
// Store loop per iter: 3 readlane + 1 cvt + 4 fma + 1 nt-store (~20 cy).
template<int FP8>
__global__ __launch_bounds__(256) void k_main(const float* __restrict__ emb,
                                              const unsigned char* __restrict__ emb8,
                                              const int* __restrict__ seq,
                                              const int* __restrict__ seq_l,
                                              const float* __restrict__ t2,
                                              const float* __restrict__ sbuf,
                                              float* __restrict__ out) {
    const int wid  = (blockIdx.x * blockDim.x + threadIdx.x) >> 6;
    const int lane = threadIdx.x & 63;
    const int n_chunks = GAT_L / CHUNK;               // 32
    const int b  = wid / n_chunks;
    const int l0 = (wid - b * n_chunks) * CHUNK;
    if (b >= GAT_B) return;

    const int sl = __builtin_amdgcn_readfirstlane(seq_l[b]);
    const float S2 = sbuf[0];

    // Lane i (i<=CHUNK) -> token l0+i; higher lanes duplicate lane CHUNK.
    // Last chunk clamps 512->511; that slot feeds only position 511's "next",
    // consumed only if valid(l=511) -- impossible since sl <= 511.
    int li = l0 + (lane < CHUNK + 1 ? lane : CHUNK);
    if (li > GAT_L - 1) li = GAT_L - 1;
    const int   tokv = seq[b * GAT_L + li];
    const float t2v  = t2[tokv];                      // one 4 B gather

    float2* obase = (float2*)(out + ((size_t)b * GAT_L + l0) * GAT_H);

    // ---- per-position pass (lanes 0..CHUNK-1 meaningful) ----
    const float t2nx  = __shfl_down(t2v, 1, 64);      // t2 of token l0+lane+1
    const int   l     = l0 + lane;
    const bool  valid = (l < sl - 1);
    const float delta = t2v - t2nx + S2;              // s0 - s1
    const float ex    = __expf(delta);
    float att1 = 1.0f / (1.0f + ex);
    att1 = valid ? att1 : 0.0f;
    const float att0 = 1.0f - att1;                   // invalid -> exactly 1
    const float cc   = valid ? ((float)(sl - l) - att1) : 0.0f;

    if constexpr (FP8) {
        unsigned short rows[CHUNK + 1];               // 2 fp8 elems per lane
        #pragma unroll
        for (int k = 0; k <= CHUNK; ++k) {
            const int tk = __builtin_amdgcn_readlane(tokv, k);   // SGPR base
            rows[k] = *((const unsigned short*)(emb8 + (size_t)tk * GAT_H) + lane);
        }
        #pragma unroll
        for (int k = 0; k < CHUNK; ++k) {
            const float a0 = readlane_f(att0, k);
            const float a1 = readlane_f(att1, k);
            const float c  = readlane_f(cc, k);
            const v2f R  = __builtin_amdgcn_cvt_pk_f32_fp8((int)rows[k],     false);
            const v2f Rn = __builtin_amdgcn_cvt_pk_f32_fp8((int)rows[k + 1], false);
            v2f o2;
            o2.x = fmaf(a0, R.x, fmaf(a1, Rn.x, c));
            o2.y = fmaf(a0, R.y, fmaf(a1, Rn.y, c));
            __builtin_nontemporal_store(o2, (v2f*)(obase + (size_t)k * 64 + lane));
        }
    } else {
        float2 rows[CHUNK + 1];
        #pragma unroll
        for (int k = 0; k <= CHUNK; ++k) {
            const int tk = __builtin_amdgcn_readlane(tokv, k);
            rows[k] = ((const float2*)(emb + (size_t)tk * GAT_H))[lane];
        }
        #pragma unroll
        for (int k = 0; k < CHUNK; ++k) {
            const float a0 = readlane_f(att0, k);
            const float a1 = readlane_f(att1, k);
            const float c  = readlane_f(cc, k);
            const float2 R  = rows[k];
            const float2 Rn = rows[k + 1];
            v2f o2;
            o2.x = fmaf(a0, R.x, fmaf(a1, Rn.x, c));
            o2.y = fmaf(a0, R.y, fmaf(a1, Rn.y, c));
            __builtin_nontemporal_store(o2, (v2f*)(obase + (size_t)k * 64 + lane));
        }
    }
}

extern "C" void kernel_launch(void* const* d_in, const int* in_sizes, int n_in,
                              void* d_out, int out_size, void* d_ws, size_t ws_size,
                              hipStream_t stream) {
    const float* emb   = (const float*)d_in[0];
    const float* a     = (const float*)d_in[1];
    const int*   seq   = (const int*)d_in[2];
    const int*   seq_l = (const int*)d_in[3];
    float* out = (float*)d_out;

    const size_t emb8_bytes = (size_t)V_TOK * GAT_H;                    // 12.8 MB
    const size_t t2_bytes   = (size_t)V_TOK * sizeof(float);            // 400 KB
    const size_t need8      = emb8_bytes + t2_bytes + 16;

    const int tok_waves  = V_TOK / 2 + 1;
    const int tok_blocks = (tok_waves * 64 + 255) / 256;
    const int main_waves  = GAT_B * (GAT_L / CHUNK);
    const int main_blocks = (main_waves * 64 + 255) / 256;

    if (ws_size >= need8) {
        unsigned char* emb8 = (unsigned char*)d_ws;
        float* t2   = (float*)((char*)d_ws + emb8_bytes);
        float* sbuf = (float*)((char*)t2 + t2_bytes);
        k_tok<1><<<tok_blocks, 256, 0, stream>>>(emb, a, t2, emb8, sbuf);
        k_main<1><<<main_blocks, 256, 0, stream>>>(emb, emb8, seq, seq_l, t2, sbuf, out);
    } else {
        // f32 fallback if workspace can't hold the shadow
        float* t2   = (float*)d_ws;
        float* sbuf = (float*)((char*)t2 + t2_bytes);
        k_tok<0><<<tok_blocks, 256, 0, stream>>>(emb, a, t2, nullptr, sbuf);
        k_main<0><<<main_blocks, 256, 0, stream>>>(emb, nullptr, seq, seq_l, t2, sbuf, out);
    }
}